// Round 1
// baseline (349.657 us; speedup 1.0000x reference)
//
#include <hip/hip_runtime.h>

#define IMG_H 512
#define IMG_W 512
#define PAD   256      // max_size = GS * 2^(N_GLIMPSES-1)
#define HP    1024     // padded height/width
#define BATCH 64
#define KTOT  36864    // 64*64*9 contraction length
#define KTILE 128      // K per GEMM block
#define KB    16       // K per LDS chunk
#define NTILES 288     // KTOT / KTILE

// Keys cubic kernel, a = -0.5 (matches jax.image resize 'cubic')
__device__ __forceinline__ float keys_cubic(float x) {
  if (x >= 2.0f) return 0.0f;
  if (x >= 1.0f) return ((-0.5f * x + 2.5f) * x - 4.0f) * x + 2.0f;
  return ((1.5f * x - 2.5f) * x) * x + 1.0f;
}

// Separable antialiased bicubic downsample of an S x S crop (S = 64*KS) to 64x64,
// one output row y per block. KS = inv_scale = kernel_scale (2 or 4).
template <int KS>
__device__ __forceinline__ void glimpse_resize_body(
    const float* __restrict__ imb, int b, int y, int tly, int tlx,
    float* __restrict__ G, int tid, float* tmp) {
  constexpr int S  = 64 * KS;
  constexpr int NT = 4 * KS;  // tap count: support |x|<2 scaled by KS
  const float fks = (float)KS;

  // ---- weights for this output row (normalized over in-range taps) ----
  float sy  = ((float)y + 0.5f) * fks - 0.5f;  // sample_f
  int   iy0 = (int)ceilf(sy - 2.0f * fks);     // first tap index
  float wy[NT];
  float wsum = 0.0f;
#pragma unroll
  for (int t = 0; t < NT; ++t) {
    int i = iy0 + t;
    float w = 0.0f;
    if (i >= 0 && i < S) w = keys_cubic(fabsf(sy - (float)i) / fks);
    wy[t] = w;
    wsum += w;
  }
  float winv = 1.0f / wsum;
#pragma unroll
  for (int t = 0; t < NT; ++t) wy[t] *= winv;

  // ---- vertical pass: tmp[x*3+c], x in [0,S) ----
  for (int e = tid; e < S * 3; e += 256) {
    int xcol = e / 3;
    int c    = e - 3 * xcol;
    int px   = tlx - PAD + xcol;  // image column
    float a = 0.0f;
    if ((unsigned)px < (unsigned)IMG_W) {
      const float* colp = imb + (px * 3 + c);
#pragma unroll
      for (int t = 0; t < NT; ++t) {
        int py = tly + iy0 + t - PAD;  // image row (zeros outside)
        if ((unsigned)py < (unsigned)IMG_H)
          a = fmaf(wy[t], colp[py * (IMG_W * 3)], a);
      }
    }
    tmp[e] = a;
  }
  __syncthreads();

  // ---- horizontal pass: 64 outputs x 3 channels ----
  if (tid < 192) {
    int xo = tid / 3;
    int c  = tid - 3 * xo;
    float sx  = ((float)xo + 0.5f) * fks - 0.5f;
    int   ix0 = (int)ceilf(sx - 2.0f * fks);
    float a = 0.0f, wsx = 0.0f;
#pragma unroll
    for (int t = 0; t < NT; ++t) {
      int i = ix0 + t;
      if (i >= 0 && i < S) {
        float w = keys_cubic(fabsf(sx - (float)i) / fks);
        wsx += w;
        a = fmaf(w, tmp[i * 3 + c], a);
      }
    }
    constexpr int sc = (KS == 2) ? 1 : 2;
    G[(((size_t)b * 64 + y) * 64 + xo) * 9 + 3 * sc + c] = a / wsx;
  }
}

// grid: BATCH * 3 scales * 64 rows = 12288 blocks, 256 threads
__global__ __launch_bounds__(256) void glimpse_kernel(
    const float* __restrict__ img, const float* __restrict__ loc,
    float* __restrict__ G) {
  __shared__ float tmp[768];  // up to S*3 = 768 floats
  int blk = blockIdx.x;
  int y   = blk & 63;
  int t3  = blk >> 6;
  int sc  = t3 % 3;
  int b   = t3 / 3;
  int tid = threadIdx.x;

  // center / top-left: bit-identical to reference fp32 math, banker's rounding
  float cy = (loc[2 * b] + 1.0f) * 0.5f * 1024.0f;
  float cx = (loc[2 * b + 1] + 1.0f) * 0.5f * 1024.0f;
  int s   = 64 << sc;
  int tly = min(max((int)rintf(cy - 0.5f * (float)s), 0), HP - s);
  int tlx = min(max((int)rintf(cx - 0.5f * (float)s), 0), HP - s);
  const float* imb = img + (size_t)b * (IMG_H * IMG_W * 3);

  if (sc == 0) {
    // 64 -> 64 resize is exactly identity: direct (zero-padded) crop copy
    if (tid < 192) {
      int x = tid / 3, c = tid - 3 * (tid / 3);
      int py = tly + y - PAD, px = tlx + x - PAD;
      float v = 0.0f;
      if ((unsigned)py < (unsigned)IMG_H && (unsigned)px < (unsigned)IMG_W)
        v = imb[(py * IMG_W + px) * 3 + c];
      G[(((size_t)b * 64 + y) * 64 + x) * 9 + c] = v;
    }
  } else if (sc == 1) {
    glimpse_resize_body<2>(imb, b, y, tly, tlx, G, tid, tmp);
  } else {
    glimpse_resize_body<4>(imb, b, y, tly, tlx, G, tid, tmp);
  }
}

// Split-K GEMM: x1_partial[tile] = G[64, Ktile] @ Wg[Ktile, 128]
// grid: NTILES blocks x 256 threads; each block covers full M=64, N=128.
__global__ __launch_bounds__(256) void gemm_kernel(
    const float* __restrict__ G, const float* __restrict__ Wg,
    float* __restrict__ partials) {
  const int tile = blockIdx.x;
  const int tid  = threadIdx.x;
  const int tn   = tid & 15;  // n = tn*8 .. +7
  const int tm   = tid >> 4;  // m = tm*4 .. +3
  __shared__ float Gs[KB][64];
  __shared__ float Ws[KB][128];

  const int gb = tid >> 2;         // batch row for G load
  const int gj = (tid & 3) * 4;    // k offset for G load
  const int wr = tid >> 4;         // k row for Wg load
  const int wc = (tid & 15) * 8;   // n col for Wg load
  const size_t gbase = (size_t)gb * KTOT + (size_t)tile * KTILE + gj;
  const size_t wbase = ((size_t)tile * KTILE + wr) * 128 + wc;

  // register prefetch of chunk 0
  float4 g4 = *(const float4*)(G + gbase);
  float4 wa = *(const float4*)(Wg + wbase);
  float4 wb = *(const float4*)(Wg + wbase + 4);

  float acc[4][8];
#pragma unroll
  for (int mi = 0; mi < 4; ++mi)
#pragma unroll
    for (int ni = 0; ni < 8; ++ni) acc[mi][ni] = 0.0f;

  constexpr int NCHUNK = KTILE / KB;  // 8
#pragma unroll
  for (int chunk = 0; chunk < NCHUNK; ++chunk) {
    Gs[gj + 0][gb] = g4.x;
    Gs[gj + 1][gb] = g4.y;
    Gs[gj + 2][gb] = g4.z;
    Gs[gj + 3][gb] = g4.w;
    *(float4*)&Ws[wr][wc]     = wa;
    *(float4*)&Ws[wr][wc + 4] = wb;
    __syncthreads();
    if (chunk + 1 < NCHUNK) {  // prefetch next chunk while computing this one
      g4 = *(const float4*)(G + gbase + (chunk + 1) * KB);
      wa = *(const float4*)(Wg + wbase + (size_t)(chunk + 1) * KB * 128);
      wb = *(const float4*)(Wg + wbase + (size_t)(chunk + 1) * KB * 128 + 4);
    }
#pragma unroll
    for (int j = 0; j < KB; ++j) {
      float4 gv = *(const float4*)&Gs[j][tm * 4];
      float4 w0 = *(const float4*)&Ws[j][tn * 8];
      float4 w1 = *(const float4*)&Ws[j][tn * 8 + 4];
      float gm[4] = {gv.x, gv.y, gv.z, gv.w};
      float wn[8] = {w0.x, w0.y, w0.z, w0.w, w1.x, w1.y, w1.z, w1.w};
#pragma unroll
      for (int mi = 0; mi < 4; ++mi)
#pragma unroll
        for (int ni = 0; ni < 8; ++ni)
          acc[mi][ni] = fmaf(gm[mi], wn[ni], acc[mi][ni]);
    }
    __syncthreads();
  }

#pragma unroll
  for (int mi = 0; mi < 4; ++mi) {
    int m = tm * 4 + mi;
    float4 v0 = make_float4(acc[mi][0], acc[mi][1], acc[mi][2], acc[mi][3]);
    float4 v1 = make_float4(acc[mi][4], acc[mi][5], acc[mi][6], acc[mi][7]);
    float* dst = partials + ((size_t)tile * 64 + m) * 128 + tn * 8;
    *(float4*)dst       = v0;
    *(float4*)(dst + 4) = v1;
  }
}

// Reduce split-K partials, add biases, fuse loc branch and output layer.
// grid: 64 blocks (one per batch) x 256 threads
__global__ __launch_bounds__(256) void finalize_kernel(
    const float* __restrict__ partials, const float* __restrict__ loc,
    const float* __restrict__ bg, const float* __restrict__ Wl,
    const float* __restrict__ bl, const float* __restrict__ Wo,
    const float* __restrict__ bo, float* __restrict__ out) {
  int b   = blockIdx.x;
  int tid = threadIdx.x;
  int k    = tid & 127;
  int half = tid >> 7;

  float s = 0.0f;
  for (int t = half; t < NTILES; t += 2)
    s += partials[((size_t)t * 64 + b) * 128 + k];

  __shared__ float red[256];
  __shared__ float h[128];
  red[tid] = s;
  __syncthreads();
  if (tid < 128) {
    float ss = red[tid] + red[tid + 128];
    float x1 = fmaxf(ss + bg[tid], 0.0f);
    float x2 = fmaxf(fmaf(loc[2 * b], Wl[tid],
                          fmaf(loc[2 * b + 1], Wl[128 + tid], bl[tid])),
                     0.0f);
    h[tid] = x1 + x2;
  }
  __syncthreads();
  {
    int n = tid;  // 256 outputs
    float a = bo[n];
#pragma unroll 8
    for (int kk = 0; kk < 128; ++kk) a = fmaf(h[kk], Wo[kk * 256 + n], a);
    out[(size_t)b * 256 + n] = fmaxf(a, 0.0f);
  }
}

extern "C" void kernel_launch(void* const* d_in, const int* in_sizes, int n_in,
                              void* d_out, int out_size, void* d_ws, size_t ws_size,
                              hipStream_t stream) {
  const float* img = (const float*)d_in[0];
  const float* loc = (const float*)d_in[1];
  const float* Wg  = (const float*)d_in[2];
  const float* bg  = (const float*)d_in[3];
  const float* Wl  = (const float*)d_in[4];
  const float* bl  = (const float*)d_in[5];
  const float* Wo  = (const float*)d_in[6];
  const float* bo  = (const float*)d_in[7];
  float* out = (float*)d_out;

  float* ws = (float*)d_ws;
  float* G        = ws;             // 64*64*64*9   = 2359296 floats (9.4 MB)
  float* partials = ws + 2359296;   // 288*64*128   = 2359296 floats (9.4 MB)

  glimpse_kernel<<<BATCH * 3 * 64, 256, 0, stream>>>(img, loc, G);
  gemm_kernel<<<NTILES, 256, 0, stream>>>(G, Wg, partials);
  finalize_kernel<<<BATCH, 256, 0, stream>>>(partials, loc, bg, Wl, bl, Wo, bo, out);
}

// Round 2
// 344.054 us; speedup vs baseline: 1.0163x; 1.0163x over previous
//
#include <hip/hip_runtime.h>

#define IMG_H 512
#define IMG_W 512
#define PAD   256      // max_size = GS * 2^(N_GLIMPSES-1)
#define HP    1024     // padded height/width
#define BATCH 64
#define KTOT  36864    // 64*64*9 contraction length
#define KTILE 144      // K per GEMM block (36864 / 256)
#define KB    16       // K per LDS chunk
#define NTILES 256     // KTOT / KTILE  -> exactly 1 block per CU

// Keys cubic kernel, a = -0.5 (matches jax.image resize 'cubic')
__device__ __forceinline__ float keys_cubic(float x) {
  if (x >= 2.0f) return 0.0f;
  if (x >= 1.0f) return ((-0.5f * x + 2.5f) * x - 4.0f) * x + 2.0f;
  return ((1.5f * x - 2.5f) * x) * x + 1.0f;
}

// Separable antialiased bicubic downsample of an S x S crop (S = 64*KS) to 64x64,
// one output row y per block. KS = inv_scale = kernel_scale (2 or 4).
template <int KS>
__device__ __forceinline__ void glimpse_resize_body(
    const float* __restrict__ imb, int b, int y, int tly, int tlx,
    float* __restrict__ G, int tid, float* tmp) {
  constexpr int S  = 64 * KS;
  constexpr int NT = 4 * KS;  // tap count: support |x|<2 scaled by KS
  const float fks = (float)KS;

  // ---- weights for this output row (normalized over in-range taps) ----
  float sy  = ((float)y + 0.5f) * fks - 0.5f;  // sample_f
  int   iy0 = (int)ceilf(sy - 2.0f * fks);     // first tap index
  float wy[NT];
  float wsum = 0.0f;
#pragma unroll
  for (int t = 0; t < NT; ++t) {
    int i = iy0 + t;
    float w = 0.0f;
    if (i >= 0 && i < S) w = keys_cubic(fabsf(sy - (float)i) / fks);
    wy[t] = w;
    wsum += w;
  }
  float winv = 1.0f / wsum;
#pragma unroll
  for (int t = 0; t < NT; ++t) wy[t] *= winv;

  // ---- vertical pass: tmp[x*3+c], x in [0,S) ----
  for (int e = tid; e < S * 3; e += 256) {
    int xcol = e / 3;
    int c    = e - 3 * xcol;
    int px   = tlx - PAD + xcol;  // image column
    float a = 0.0f;
    if ((unsigned)px < (unsigned)IMG_W) {
      const float* colp = imb + (px * 3 + c);
#pragma unroll
      for (int t = 0; t < NT; ++t) {
        int py = tly + iy0 + t - PAD;  // image row (zeros outside)
        if ((unsigned)py < (unsigned)IMG_H)
          a = fmaf(wy[t], colp[py * (IMG_W * 3)], a);
      }
    }
    tmp[e] = a;
  }
  __syncthreads();

  // ---- horizontal pass: 64 outputs x 3 channels ----
  if (tid < 192) {
    int xo = tid / 3;
    int c  = tid - 3 * xo;
    float sx  = ((float)xo + 0.5f) * fks - 0.5f;
    int   ix0 = (int)ceilf(sx - 2.0f * fks);
    float a = 0.0f, wsx = 0.0f;
#pragma unroll
    for (int t = 0; t < NT; ++t) {
      int i = ix0 + t;
      if (i >= 0 && i < S) {
        float w = keys_cubic(fabsf(sx - (float)i) / fks);
        wsx += w;
        a = fmaf(w, tmp[i * 3 + c], a);
      }
    }
    constexpr int sc = (KS == 2) ? 1 : 2;
    G[(((size_t)b * 64 + y) * 64 + xo) * 9 + 3 * sc + c] = a / wsx;
  }
}

// grid: BATCH * 3 scales * 64 rows = 12288 blocks, 256 threads
__global__ __launch_bounds__(256) void glimpse_kernel(
    const float* __restrict__ img, const float* __restrict__ loc,
    float* __restrict__ G) {
  __shared__ float tmp[768];  // up to S*3 = 768 floats
  int blk = blockIdx.x;
  int y   = blk & 63;
  int t3  = blk >> 6;
  int sc  = t3 % 3;
  int b   = t3 / 3;
  int tid = threadIdx.x;

  // center / top-left: bit-identical to reference fp32 math, banker's rounding
  float cy = (loc[2 * b] + 1.0f) * 0.5f * 1024.0f;
  float cx = (loc[2 * b + 1] + 1.0f) * 0.5f * 1024.0f;
  int s   = 64 << sc;
  int tly = min(max((int)rintf(cy - 0.5f * (float)s), 0), HP - s);
  int tlx = min(max((int)rintf(cx - 0.5f * (float)s), 0), HP - s);
  const float* imb = img + (size_t)b * (IMG_H * IMG_W * 3);

  if (sc == 0) {
    // 64 -> 64 resize is exactly identity: direct (zero-padded) crop copy
    if (tid < 192) {
      int x = tid / 3, c = tid - 3 * (tid / 3);
      int py = tly + y - PAD, px = tlx + x - PAD;
      float v = 0.0f;
      if ((unsigned)py < (unsigned)IMG_H && (unsigned)px < (unsigned)IMG_W)
        v = imb[(py * IMG_W + px) * 3 + c];
      G[(((size_t)b * 64 + y) * 64 + x) * 9 + c] = v;
    }
  } else if (sc == 1) {
    glimpse_resize_body<2>(imb, b, y, tly, tlx, G, tid, tmp);
  } else {
    glimpse_resize_body<4>(imb, b, y, tly, tlx, G, tid, tmp);
  }
}

// Split-K GEMM: partial[b][tile][n] = G[64, Ktile] @ Wg[Ktile, 128]
// grid: NTILES blocks x 256 threads; each block covers full M=64, N=128.
// LDS double-buffered: one __syncthreads per 16-K chunk.
__global__ __launch_bounds__(256) void gemm_kernel(
    const float* __restrict__ G, const float* __restrict__ Wg,
    float* __restrict__ partials) {
  const int tile = blockIdx.x;
  const int tid  = threadIdx.x;
  const int tn   = tid & 15;  // n = tn*8 .. +7
  const int tm   = tid >> 4;  // m = tm*4 .. +3
  __shared__ float Gs[2][KB][64];
  __shared__ float Ws[2][KB][128];

  const int gb = tid >> 2;         // batch row for G load
  const int gj = (tid & 3) * 4;    // k offset for G load
  const int wr = tid >> 4;         // k row for Wg load
  const int wc = (tid & 15) * 8;   // n col for Wg load
  const size_t gbase = (size_t)gb * KTOT + (size_t)tile * KTILE + gj;
  const size_t wbase = ((size_t)tile * KTILE + wr) * 128 + wc;

  // register prefetch of chunk 0
  float4 g4 = *(const float4*)(G + gbase);
  float4 wa = *(const float4*)(Wg + wbase);
  float4 wb = *(const float4*)(Wg + wbase + 4);

  float acc[4][8];
#pragma unroll
  for (int mi = 0; mi < 4; ++mi)
#pragma unroll
    for (int ni = 0; ni < 8; ++ni) acc[mi][ni] = 0.0f;

  constexpr int NCHUNK = KTILE / KB;  // 9
#pragma unroll
  for (int chunk = 0; chunk < NCHUNK; ++chunk) {
    const int buf = chunk & 1;
    Gs[buf][gj + 0][gb] = g4.x;
    Gs[buf][gj + 1][gb] = g4.y;
    Gs[buf][gj + 2][gb] = g4.z;
    Gs[buf][gj + 3][gb] = g4.w;
    *(float4*)&Ws[buf][wr][wc]     = wa;
    *(float4*)&Ws[buf][wr][wc + 4] = wb;
    __syncthreads();
    if (chunk + 1 < NCHUNK) {  // prefetch next chunk while computing this one
      g4 = *(const float4*)(G + gbase + (chunk + 1) * KB);
      wa = *(const float4*)(Wg + wbase + (size_t)(chunk + 1) * KB * 128);
      wb = *(const float4*)(Wg + wbase + (size_t)(chunk + 1) * KB * 128 + 4);
    }
#pragma unroll
    for (int j = 0; j < KB; ++j) {
      float4 gv = *(const float4*)&Gs[buf][j][tm * 4];
      float4 w0 = *(const float4*)&Ws[buf][j][tn * 8];
      float4 w1 = *(const float4*)&Ws[buf][j][tn * 8 + 4];
      float gm[4] = {gv.x, gv.y, gv.z, gv.w};
      float wn[8] = {w0.x, w0.y, w0.z, w0.w, w1.x, w1.y, w1.z, w1.w};
#pragma unroll
      for (int mi = 0; mi < 4; ++mi)
#pragma unroll
        for (int ni = 0; ni < 8; ++ni)
          acc[mi][ni] = fmaf(gm[mi], wn[ni], acc[mi][ni]);
    }
    // no trailing sync needed: next chunk writes the other buffer, and the
    // chunk-after-next's overwrite is fenced by the next chunk's barrier.
  }

#pragma unroll
  for (int mi = 0; mi < 4; ++mi) {
    int m = tm * 4 + mi;
    // partials layout [b][tile][n] -> finalize reads one contiguous 128 KB run
    float* dst = partials + ((size_t)m * NTILES + tile) * 128 + tn * 8;
    *(float4*)dst       = make_float4(acc[mi][0], acc[mi][1], acc[mi][2], acc[mi][3]);
    *(float4*)(dst + 4) = make_float4(acc[mi][4], acc[mi][5], acc[mi][6], acc[mi][7]);
  }
}

// Reduce split-K partials, add biases, fuse loc branch and output layer.
// grid: 64 blocks (one per batch) x 256 threads; each block reads a fully
// contiguous NTILES*128*4 = 128 KB slab.
__global__ __launch_bounds__(256) void finalize_kernel(
    const float* __restrict__ partials, const float* __restrict__ loc,
    const float* __restrict__ bg, const float* __restrict__ Wl,
    const float* __restrict__ bl, const float* __restrict__ Wo,
    const float* __restrict__ bo, float* __restrict__ out) {
  int b   = blockIdx.x;
  int tid = threadIdx.x;
  int k    = tid & 127;
  int half = tid >> 7;

  const float* base = partials + (size_t)b * NTILES * 128;
  float s = 0.0f;
  for (int t = half; t < NTILES; t += 2)
    s += base[t * 128 + k];

  __shared__ float red[256];
  __shared__ float h[128];
  red[tid] = s;
  __syncthreads();
  if (tid < 128) {
    float ss = red[tid] + red[tid + 128];
    float x1 = fmaxf(ss + bg[tid], 0.0f);
    float x2 = fmaxf(fmaf(loc[2 * b], Wl[tid],
                          fmaf(loc[2 * b + 1], Wl[128 + tid], bl[tid])),
                     0.0f);
    h[tid] = x1 + x2;
  }
  __syncthreads();
  {
    int n = tid;  // 256 outputs
    float a = bo[n];
#pragma unroll 8
    for (int kk = 0; kk < 128; ++kk) a = fmaf(h[kk], Wo[kk * 256 + n], a);
    out[(size_t)b * 256 + n] = fmaxf(a, 0.0f);
  }
}

extern "C" void kernel_launch(void* const* d_in, const int* in_sizes, int n_in,
                              void* d_out, int out_size, void* d_ws, size_t ws_size,
                              hipStream_t stream) {
  const float* img = (const float*)d_in[0];
  const float* loc = (const float*)d_in[1];
  const float* Wg  = (const float*)d_in[2];
  const float* bg  = (const float*)d_in[3];
  const float* Wl  = (const float*)d_in[4];
  const float* bl  = (const float*)d_in[5];
  const float* Wo  = (const float*)d_in[6];
  const float* bo  = (const float*)d_in[7];
  float* out = (float*)d_out;

  float* ws = (float*)d_ws;
  float* G        = ws;             // 64*64*64*9     = 2359296 floats (9.4 MB)
  float* partials = ws + 2359296;   // 64*256*128     = 2097152 floats (8.4 MB)

  glimpse_kernel<<<BATCH * 3 * 64, 256, 0, stream>>>(img, loc, G);
  gemm_kernel<<<NTILES, 256, 0, stream>>>(G, Wg, partials);
  finalize_kernel<<<BATCH, 256, 0, stream>>>(partials, loc, bg, Wl, bl, Wo, bo, out);
}

// Round 3
// 318.833 us; speedup vs baseline: 1.0967x; 1.0791x over previous
//
#include <hip/hip_runtime.h>

#define IMG_H 512
#define IMG_W 512
#define PAD   256      // max_size = GS * 2^(N_GLIMPSES-1)
#define HP    1024     // padded height/width
#define BATCH 64
#define KTOT  36864    // 64*64*9 contraction length
#define KTILE 144      // K per GEMM block (36864 / 256)
#define KB    16       // K per LDS chunk
#define NTILES 256     // KTOT / KTILE  -> exactly 1 block per CU

// Keys cubic kernel, a = -0.5 (matches jax.image resize 'cubic')
__device__ __forceinline__ float keys_cubic(float x) {
  if (x >= 2.0f) return 0.0f;
  if (x >= 1.0f) return ((-0.5f * x + 2.5f) * x - 4.0f) * x + 2.0f;
  return ((1.5f * x - 2.5f) * x) * x + 1.0f;
}

__device__ __forceinline__ int iclamp(int v, int lo, int hi) {
  return min(max(v, lo), hi);
}

// One block per (b, y): computes all 3 scales of output row y for batch b.
// grid: BATCH * 64 = 4096 blocks, 256 threads
__global__ __launch_bounds__(256) void glimpse_kernel(
    const float* __restrict__ img, const float* __restrict__ loc,
    float* __restrict__ G) {
  __shared__ float tmp1[384];  // sc=1 vertical result: S=128 cols x 3 ch
  __shared__ float tmp2[768];  // sc=2 vertical result: S=256 cols x 3 ch
  const int y   = blockIdx.x & 63;
  const int b   = blockIdx.x >> 6;
  const int tid = threadIdx.x;

  // center / top-left: bit-identical to reference fp32 math, banker's rounding
  const float cy = (loc[2 * b] + 1.0f) * 0.5f * 1024.0f;
  const float cx = (loc[2 * b + 1] + 1.0f) * 0.5f * 1024.0f;
  const int tly0 = iclamp((int)rintf(cy - 32.0f), 0, HP - 64);
  const int tlx0 = iclamp((int)rintf(cx - 32.0f), 0, HP - 64);
  const int tly1 = iclamp((int)rintf(cy - 64.0f), 0, HP - 128);
  const int tlx1 = iclamp((int)rintf(cx - 64.0f), 0, HP - 128);
  const int tly2 = iclamp((int)rintf(cy - 128.0f), 0, HP - 256);
  const int tlx2 = iclamp((int)rintf(cx - 128.0f), 0, HP - 256);
  const float* imb  = img + (size_t)b * (IMG_H * IMG_W * 3);
  float*       Grow = G + ((size_t)b * 64 + y) * (64 * 9);

  // ---- scale 0: 64->64 resize is exactly identity: zero-padded crop copy ----
  if (tid < 192) {
    int x = tid / 3, c = tid - 3 * (tid / 3);
    int py = tly0 + y - PAD, px = tlx0 + x - PAD;
    float v = 0.0f;
    if ((unsigned)py < (unsigned)IMG_H && (unsigned)px < (unsigned)IMG_W)
      v = imb[(py * IMG_W + px) * 3 + c];
    Grow[x * 9 + c] = v;
  }

  // ---- vertical weights (normalized over in-range taps) ----
  float wy1[8];
  int iy0_1;
  {
    float sy = ((float)y + 0.5f) * 2.0f - 0.5f;
    iy0_1 = (int)ceilf(sy - 4.0f);
    float ws = 0.0f;
#pragma unroll
    for (int t = 0; t < 8; ++t) {
      int i = iy0_1 + t;
      float w = (i >= 0 && i < 128) ? keys_cubic(fabsf(sy - (float)i) * 0.5f) : 0.0f;
      wy1[t] = w;
      ws += w;
    }
    float wi = 1.0f / ws;
#pragma unroll
    for (int t = 0; t < 8; ++t) wy1[t] *= wi;
  }
  float wy2[16];
  int iy0_2;
  {
    float sy = ((float)y + 0.5f) * 4.0f - 0.5f;
    iy0_2 = (int)ceilf(sy - 8.0f);
    float ws = 0.0f;
#pragma unroll
    for (int t = 0; t < 16; ++t) {
      int i = iy0_2 + t;
      float w = (i >= 0 && i < 256) ? keys_cubic(fabsf(sy - (float)i) * 0.25f) : 0.0f;
      wy2[t] = w;
      ws += w;
    }
    float wi = 1.0f / ws;
#pragma unroll
    for (int t = 0; t < 16; ++t) wy2[t] *= wi;
  }

  // ---- vertical pass, scale 1: 384 elements ----
  for (int e = tid; e < 384; e += 256) {
    int x = e / 3, c = e - 3 * (e / 3);
    int px = tlx1 - PAD + x;
    float a = 0.0f;
    if ((unsigned)px < (unsigned)IMG_W) {
      const float* colp = imb + (px * 3 + c);
#pragma unroll
      for (int t = 0; t < 8; ++t) {
        int py = tly1 + iy0_1 + t - PAD;
        if ((unsigned)py < (unsigned)IMG_H)
          a = fmaf(wy1[t], colp[py * (IMG_W * 3)], a);
      }
    }
    tmp1[e] = a;
  }
  // ---- vertical pass, scale 2: 768 elements ----
  for (int e = tid; e < 768; e += 256) {
    int x = e / 3, c = e - 3 * (e / 3);
    int px = tlx2 - PAD + x;
    float a = 0.0f;
    if ((unsigned)px < (unsigned)IMG_W) {
      const float* colp = imb + (px * 3 + c);
#pragma unroll
      for (int t = 0; t < 16; ++t) {
        int py = tly2 + iy0_2 + t - PAD;
        if ((unsigned)py < (unsigned)IMG_H)
          a = fmaf(wy2[t], colp[py * (IMG_W * 3)], a);
      }
    }
    tmp2[e] = a;
  }
  __syncthreads();

  // ---- horizontal pass, both scales: 384 outputs, wave-uniform branches ----
  for (int o = tid; o < 384; o += 256) {
    int oo = (o >= 192) ? o - 192 : o;
    int xo = oo / 3, c = oo - 3 * xo;
    if (o < 192) {  // scale 1 (KS=2)
      float sx  = ((float)xo + 0.5f) * 2.0f - 0.5f;
      int   ix0 = (int)ceilf(sx - 4.0f);
      float a = 0.0f, wsx = 0.0f;
#pragma unroll
      for (int t = 0; t < 8; ++t) {
        int i = ix0 + t;
        if (i >= 0 && i < 128) {
          float w = keys_cubic(fabsf(sx - (float)i) * 0.5f);
          wsx += w;
          a = fmaf(w, tmp1[i * 3 + c], a);
        }
      }
      Grow[xo * 9 + 3 + c] = a / wsx;
    } else {        // scale 2 (KS=4)
      float sx  = ((float)xo + 0.5f) * 4.0f - 0.5f;
      int   ix0 = (int)ceilf(sx - 8.0f);
      float a = 0.0f, wsx = 0.0f;
#pragma unroll
      for (int t = 0; t < 16; ++t) {
        int i = ix0 + t;
        if (i >= 0 && i < 256) {
          float w = keys_cubic(fabsf(sx - (float)i) * 0.25f);
          wsx += w;
          a = fmaf(w, tmp2[i * 3 + c], a);
        }
      }
      Grow[xo * 9 + 6 + c] = a / wsx;
    }
  }
}

// Split-K GEMM: partial[b][tile][n] = G[64, Ktile] @ Wg[Ktile, 128]
// grid: NTILES blocks x 256 threads; each block covers full M=64, N=128.
// LDS double-buffered: one __syncthreads per 16-K chunk.
__global__ __launch_bounds__(256) void gemm_kernel(
    const float* __restrict__ G, const float* __restrict__ Wg,
    float* __restrict__ partials) {
  const int tile = blockIdx.x;
  const int tid  = threadIdx.x;
  const int tn   = tid & 15;  // n = tn*8 .. +7
  const int tm   = tid >> 4;  // m = tm*4 .. +3
  __shared__ float Gs[2][KB][64];
  __shared__ float Ws[2][KB][128];

  const int gb = tid >> 2;         // batch row for G load
  const int gj = (tid & 3) * 4;    // k offset for G load
  const int wr = tid >> 4;         // k row for Wg load
  const int wc = (tid & 15) * 8;   // n col for Wg load
  const size_t gbase = (size_t)gb * KTOT + (size_t)tile * KTILE + gj;
  const size_t wbase = ((size_t)tile * KTILE + wr) * 128 + wc;

  // register prefetch of chunk 0
  float4 g4 = *(const float4*)(G + gbase);
  float4 wa = *(const float4*)(Wg + wbase);
  float4 wb = *(const float4*)(Wg + wbase + 4);

  float acc[4][8];
#pragma unroll
  for (int mi = 0; mi < 4; ++mi)
#pragma unroll
    for (int ni = 0; ni < 8; ++ni) acc[mi][ni] = 0.0f;

  constexpr int NCHUNK = KTILE / KB;  // 9
#pragma unroll
  for (int chunk = 0; chunk < NCHUNK; ++chunk) {
    const int buf = chunk & 1;
    Gs[buf][gj + 0][gb] = g4.x;
    Gs[buf][gj + 1][gb] = g4.y;
    Gs[buf][gj + 2][gb] = g4.z;
    Gs[buf][gj + 3][gb] = g4.w;
    *(float4*)&Ws[buf][wr][wc]     = wa;
    *(float4*)&Ws[buf][wr][wc + 4] = wb;
    __syncthreads();
    if (chunk + 1 < NCHUNK) {  // prefetch next chunk while computing this one
      g4 = *(const float4*)(G + gbase + (chunk + 1) * KB);
      wa = *(const float4*)(Wg + wbase + (size_t)(chunk + 1) * KB * 128);
      wb = *(const float4*)(Wg + wbase + (size_t)(chunk + 1) * KB * 128 + 4);
    }
#pragma unroll
    for (int j = 0; j < KB; ++j) {
      float4 gv = *(const float4*)&Gs[buf][j][tm * 4];
      float4 w0 = *(const float4*)&Ws[buf][j][tn * 8];
      float4 w1 = *(const float4*)&Ws[buf][j][tn * 8 + 4];
      float gm[4] = {gv.x, gv.y, gv.z, gv.w};
      float wn[8] = {w0.x, w0.y, w0.z, w0.w, w1.x, w1.y, w1.z, w1.w};
#pragma unroll
      for (int mi = 0; mi < 4; ++mi)
#pragma unroll
        for (int ni = 0; ni < 8; ++ni)
          acc[mi][ni] = fmaf(gm[mi], wn[ni], acc[mi][ni]);
    }
    // no trailing sync needed: next chunk writes the other buffer, and the
    // chunk-after-next's overwrite is fenced by the next chunk's barrier.
  }

#pragma unroll
  for (int mi = 0; mi < 4; ++mi) {
    int m = tm * 4 + mi;
    // partials layout [b][tile][n] -> finalize reads one contiguous 128 KB slab
    float* dst = partials + ((size_t)m * NTILES + tile) * 128 + tn * 8;
    *(float4*)dst       = make_float4(acc[mi][0], acc[mi][1], acc[mi][2], acc[mi][3]);
    *(float4*)(dst + 4) = make_float4(acc[mi][4], acc[mi][5], acc[mi][6], acc[mi][7]);
  }
}

// Reduce split-K partials, add biases, fuse loc branch and output layer.
// grid: 64 blocks (one per batch) x 256 threads. Fully-coalesced float4
// streaming over the contiguous 128 KB slab; k recovered as flat & 127.
__global__ __launch_bounds__(256) void finalize_kernel(
    const float* __restrict__ partials, const float* __restrict__ loc,
    const float* __restrict__ bg, const float* __restrict__ Wl,
    const float* __restrict__ bl, const float* __restrict__ Wo,
    const float* __restrict__ bo, float* __restrict__ out) {
  const int b   = blockIdx.x;
  const int tid = threadIdx.x;

  const float4* base = (const float4*)(partials + (size_t)b * NTILES * 128);
  float4 acc = make_float4(0.f, 0.f, 0.f, 0.f);
  // NTILES*128 = 32768 floats = 8192 float4; 256 threads -> 32 sweeps.
  // flat index = i*1024 + tid*4 + j  ->  k = flat & 127 = (tid&31)*4 + j
#pragma unroll 8
  for (int i = 0; i < 32; ++i) {
    float4 v = base[(size_t)i * 256 + tid];
    acc.x += v.x; acc.y += v.y; acc.z += v.z; acc.w += v.w;
  }

  __shared__ float red[8][128];
  __shared__ float h[128];
  {
    float* r = &red[tid >> 5][(tid & 31) * 4];
    r[0] = acc.x; r[1] = acc.y; r[2] = acc.z; r[3] = acc.w;
  }
  __syncthreads();
  if (tid < 128) {
    float ss = 0.0f;
#pragma unroll
    for (int g = 0; g < 8; ++g) ss += red[g][tid];
    float x1 = fmaxf(ss + bg[tid], 0.0f);
    float x2 = fmaxf(fmaf(loc[2 * b], Wl[tid],
                          fmaf(loc[2 * b + 1], Wl[128 + tid], bl[tid])),
                     0.0f);
    h[tid] = x1 + x2;
  }
  __syncthreads();
  {
    int n = tid;  // 256 outputs
    float a = bo[n];
#pragma unroll 8
    for (int kk = 0; kk < 128; ++kk) a = fmaf(h[kk], Wo[kk * 256 + n], a);
    out[(size_t)b * 256 + n] = fmaxf(a, 0.0f);
  }
}

extern "C" void kernel_launch(void* const* d_in, const int* in_sizes, int n_in,
                              void* d_out, int out_size, void* d_ws, size_t ws_size,
                              hipStream_t stream) {
  const float* img = (const float*)d_in[0];
  const float* loc = (const float*)d_in[1];
  const float* Wg  = (const float*)d_in[2];
  const float* bg  = (const float*)d_in[3];
  const float* Wl  = (const float*)d_in[4];
  const float* bl  = (const float*)d_in[5];
  const float* Wo  = (const float*)d_in[6];
  const float* bo  = (const float*)d_in[7];
  float* out = (float*)d_out;

  float* ws = (float*)d_ws;
  float* G        = ws;             // 64*64*64*9     = 2359296 floats (9.4 MB)
  float* partials = ws + 2359296;   // 64*256*128     = 2097152 floats (8.4 MB)

  glimpse_kernel<<<BATCH * 64, 256, 0, stream>>>(img, loc, G);
  gemm_kernel<<<NTILES, 256, 0, stream>>>(G, Wg, partials);
  finalize_kernel<<<BATCH, 256, 0, stream>>>(partials, loc, bg, Wl, bl, Wo, bo, out);
}